// Round 5
// baseline (1112.064 us; speedup 1.0000x reference)
//
#include <hip/hip_runtime.h>
#include <hip/hip_bf16.h>
#include <hip/hip_fp16.h>

// ManualRNN: B=32, T=2048, Fin=256, H=256, O=256  (all f32 in/out)
//   phase1: xh = x @ Wxh^T + bxh   -> stored f32 in d_out's y region (dead before phase3)
//   phase2: h_t = tanh(xh_t + h @ Whh^T), scan over T -> hs f16 in d_ws
//   phase3: y  = hs @ Why^T + by   -> overwrites y region
// h_final (32x256 f32) at d_out + 65536*256.
//
// Scan floor: 128 MFMA/CU/step * ~4.03 cy = ~515 cy/step (r4 counters: active-CU
// MfmaUtil 53% x 960cy = 509cy, matches theoretical dense rate). Any batch
// packing / N-split keeps the same per-CU MFMA count or needs cross-CU sync.
// r5: barrier -> per-wave progress flags so waves decouple and serial phases
// hide under the sibling wave's MFMA issue.

typedef _Float16 f16x8 __attribute__((ext_vector_type(8)));
typedef float    f32x4 __attribute__((ext_vector_type(4)));

#define MFMA16 __builtin_amdgcn_mfma_f32_16x16x32_f16

__device__ __forceinline__ f16x8 cvt8(const float* __restrict__ p) {
    float4 u = *(const float4*)p;
    float4 v = *(const float4*)(p + 4);
    f16x8 r;
    r[0] = (_Float16)u.x; r[1] = (_Float16)u.y; r[2] = (_Float16)u.z; r[3] = (_Float16)u.w;
    r[4] = (_Float16)v.x; r[5] = (_Float16)v.y; r[6] = (_Float16)v.z; r[7] = (_Float16)v.w;
    return r;
}

// C[m][n] = sum_k A[m][k] * W[n][k] + bias[n];  M = gridDim.x*64, N = K = 256.
template<bool AF16>
__global__ __launch_bounds__(256, 2) void gemm_nt_256(
    const void* __restrict__ Av, const float* __restrict__ W,
    const float* __restrict__ bias, float* __restrict__ C) {
    const int tid = threadIdx.x;
    const int l  = tid & 63;
    const int w  = tid >> 6;
    const int lr = l & 15;
    const int lg = l >> 4;
    const long m0 = (long)blockIdx.x * 64;
    const int  n0 = w * 64;

    f32x4 acc[4][4] = {};

    #pragma unroll
    for (int k = 0; k < 8; ++k) {
        const int kc = k * 32 + lg * 8;
        f16x8 a[4], bf[4];
        #pragma unroll
        for (int mt = 0; mt < 4; ++mt) {
            const long row = m0 + mt * 16 + lr;
            if constexpr (AF16)
                a[mt] = *(const f16x8*)((const _Float16*)Av + row * 256 + kc);
            else
                a[mt] = cvt8((const float*)Av + row * 256 + kc);
        }
        #pragma unroll
        for (int nt = 0; nt < 4; ++nt)
            bf[nt] = cvt8(W + (long)(n0 + nt * 16 + lr) * 256 + kc);
        #pragma unroll
        for (int mt = 0; mt < 4; ++mt)
            #pragma unroll
            for (int nt = 0; nt < 4; ++nt)
                acc[mt][nt] = MFMA16(a[mt], bf[nt], acc[mt][nt], 0, 0, 0);
    }

    #pragma unroll
    for (int mt = 0; mt < 4; ++mt)
        #pragma unroll
        for (int nt = 0; nt < 4; ++nt) {
            const int col = n0 + nt * 16 + lr;
            const float bv = bias[col];
            #pragma unroll
            for (int d = 0; d < 4; ++d) {
                const long row = m0 + mt * 16 + lg * 4 + d;
                C[row * 256 + col] = acc[mt][nt][d] + bv;
            }
        }
}

// Recurrence: 32 blocks (1 batch each) x 512 threads (8 waves, 2/SIMD).
// Wave w owns output cols 32w..32w+31 == k-chunk w of next step's A fragments.
// NO barrier in loop: per-wave progress flags. Iter t protocol:
//   top:  write own h slice to hbuf[t&1]; lgkmcnt(0); flags[w]=t+1 (release)
//   own chunk (i=0, k=w): ds_read + 2 MFMA immediately (no wait needed)
//   poll: all(flags >= t+1) (LDS broadcast read, ~1 spin steady-state)
//   then chunks i=1..7 (k=(w+i)&7), tanh, hs store.
// WAR safe: flags[j]=t+1 is written after lgkmcnt(0) retires wave j's iter-(t-1)
// af reads; a wave reaches its iter t+1 write of hbuf[(t+1)&1] only after
// polling flags>=t+1, i.e. after all readers of that buffer's previous contents
// (iter t-1) retired their reads.
// Whh fragments loaded ROTATED (wbr[i] = chunk (w+i)&7) so every register
// array is statically indexed (rule #20).
__global__ __launch_bounds__(512, 1) void rnn_scan(
    const float* __restrict__ xh, const float* __restrict__ h0,
    const float* __restrict__ Whh, _Float16* __restrict__ hs,
    float* __restrict__ hfin) {
    const int b   = blockIdx.x;
    const int tid = threadIdx.x;
    const int l   = tid & 63;
    const int w   = tid >> 6;   // 0..7
    const int lr  = l & 15;
    const int lg  = l >> 4;
    const int n0  = w * 32;

    __shared__ _Float16 hbuf[2][256];
    __shared__ unsigned flags[8];

    // rotated B fragments: wbr[nt][i] = Whh[n0+nt*16+lr][k*32+lg*8..+8], k=(w+i)&7
    f16x8 wbr[2][8];
    #pragma unroll
    for (int i = 0; i < 8; ++i) {
        const int k = (w + i) & 7;
        #pragma unroll
        for (int nt = 0; nt < 2; ++nt)
            wbr[nt][i] = cvt8(Whh + (long)(n0 + nt * 16 + lr) * 256 + k * 32 + lg * 8);
    }

    if (tid < 8) flags[tid] = 0;
    __syncthreads();

    const int cl = n0 + (l & 31);
    const float* xp = xh + (long)b * 2048 * 256 + cl;
    _Float16*    hp = hs + (long)b * 2048 * 256 + cl;
    volatile unsigned* fl = flags;

    // own h value for the CURRENT step's input; published at iter top.
    _Float16 hv = (_Float16)h0[b * 256 + cl];

    float xcur[4], xnext[4];
    #pragma unroll
    for (int j = 0; j < 4; ++j) xcur[j] = xp[(long)j * 256];

    for (int tb = 0; tb < 2048; tb += 4) {
        // next group's xh loads: ~2500cy cover >> 900cy HBM latency
        #pragma unroll
        for (int j = 0; j < 4; ++j) {
            long tn = tb + 4 + j; if (tn > 2047) tn = 2047;
            xnext[j] = xp[tn * 256];
        }

        #pragma unroll
        for (int j = 0; j < 4; ++j) {
            const int t = tb + j;
            _Float16* hb = hbuf[j & 1];
            const f16x8* hc = (const f16x8*)hb;

            // publish own slice of h_t (release)
            if (l < 32) hb[cl] = hv;
            asm volatile("s_waitcnt lgkmcnt(0)" ::: "memory");
            if (l == 0) fl[w] = (unsigned)(t + 1);

            // own chunk: no wait on others
            f16x8 afr[8];
            afr[0] = hc[(w & 7) * 4 + lg];

            const f32x4 zero = {0.f, 0.f, 0.f, 0.f};
            f32x4 accA[2], accB[2];
            accA[0] = MFMA16(afr[0], wbr[0][0], zero, 0, 0, 0);
            accA[1] = MFMA16(afr[0], wbr[1][0], zero, 0, 0, 0);

            // acquire: everyone published h_t
            unsigned fv;
            do { fv = fl[l & 7]; } while (__ballot(fv > (unsigned)t) != ~0ull);

            #pragma unroll
            for (int i = 1; i < 8; ++i)
                afr[i] = hc[((w + i) & 7) * 4 + lg];

            accB[0] = MFMA16(afr[1], wbr[0][1], zero, 0, 0, 0);
            accB[1] = MFMA16(afr[1], wbr[1][1], zero, 0, 0, 0);
            #pragma unroll
            for (int i = 2; i < 8; i += 2) {
                accA[0] = MFMA16(afr[i],     wbr[0][i],     accA[0], 0, 0, 0);
                accA[1] = MFMA16(afr[i],     wbr[1][i],     accA[1], 0, 0, 0);
                accB[0] = MFMA16(afr[i + 1], wbr[0][i + 1], accB[0], 0, 0, 0);
                accB[1] = MFMA16(afr[i + 1], wbr[1][i + 1], accB[1], 0, 0, 0);
            }

            // tanh(s + xh) = 1 - 2/(exp(2s)+1); select col's sum first
            const float s0 = accA[0][0] + accB[0][0];
            const float s1 = accA[1][0] + accB[1][0];
            const float s  = ((l & 16) ? s1 : s0) + xcur[j];
            const float e  = __expf(2.0f * s);
            const float v  = 1.0f - 2.0f * __builtin_amdgcn_rcpf(e + 1.0f);
            hv = (_Float16)v;

            if (l < 32) hp[(long)t * 256] = hv;   // fire-and-forget hs store
        }

        #pragma unroll
        for (int j = 0; j < 4; ++j) xcur[j] = xnext[j];
    }

    // hv now holds h after step 2047 == h_final
    if (l < 32) hfin[b * 256 + cl] = (float)hv;
}

extern "C" void kernel_launch(void* const* d_in, const int* in_sizes, int n_in,
                              void* d_out, int out_size, void* d_ws, size_t ws_size,
                              hipStream_t stream) {
    const float* x   = (const float*)d_in[0];
    const float* h0  = (const float*)d_in[1];
    const float* Wxh = (const float*)d_in[2];
    const float* bxh = (const float*)d_in[3];
    const float* Whh = (const float*)d_in[4];
    const float* Why = (const float*)d_in[5];
    const float* by  = (const float*)d_in[6];

    float* y    = (float*)d_out;
    float* hfin = y + (long)65536 * 256;
    float* xh   = y;                       // xh scratch aliases y (dead before phase3 writes)
    _Float16* hs = (_Float16*)d_ws;

    gemm_nt_256<false><<<1024, 256, 0, stream>>>(x, Wxh, bxh, xh);
    rnn_scan<<<32, 512, 0, stream>>>(xh, h0, Whh, hs, hfin);
    gemm_nt_256<true><<<1024, 256, 0, stream>>>(hs, Why, by, y);
}